// Round 6
// baseline (1387.604 us; speedup 1.0000x reference)
//
#include <hip/hip_runtime.h>
#include <hip/hip_cooperative_groups.h>
#include <stdint.h>

namespace cg = cooperative_groups;

// No implicit FMA contraction: the JAX eager reference has none across ops;
// where XLA fuses we write fmaf() explicitly.
#pragma clang fp contract(off)

#define PDIM 162
#define NW   (2*PDIM*PDIM*3)   // 157464 words, 1.26 MB per bitboard
#define NWH  (NW/2)            // 78732
#define OD   160

// R17: single cooperative kernel.
//  - phase 0: binarize (grid-stride, wave-ballot) + zero B pads.
//  - per iter: ge2 PRE-PASS over unique cells (153.6K items, barrier-free
//    streaming -- dedups the 3.5x per-tile halo-7 recompute that was ~45% of
//    k_iter's heavy work) -> grid.sync -> R0 tile phase (16x16 core, halo 8,
//    1024 thr) minus its ge2 phase and one barrier; Ge tile loaded from the
//    precomputed board -> grid.sync.
//  - 1 launch instead of 6 (kills ~20us of gaps).
// Grid 256x1024: capacity >= 1 block/CU (VGPR forced <=128 by launch_bounds,
// LDS 49.6KB). Guard: WRITE_SIZE (scratch spill), absmax 0.
#define GRID 256
#define NTHREADS 1024
#define TZ 32
#define TY 32
#define CZ 16
#define CY 16
// 97 u64 = 194 dwords == 2 mod 32 (measured conflict-neutral, R11).
#define PZ 97
#define LADDR(lz,ly) ((lz)*PZ + (ly)*3)

// ---------------- threefry2x32, JAX partitionable scheme --------------------
__device__ __forceinline__ uint32_t rotl32(uint32_t x, uint32_t r) {
  return (x << r) | (x >> (32u - r));
}

__device__ __forceinline__ uint32_t threefry_bits(uint32_t idx) {
  const uint32_t ks0 = 0u, ks1 = 42u, ks2 = 0x1BD11BDAu ^ 0u ^ 42u;
  uint32_t x0 = 0u + ks0;
  uint32_t x1 = idx + ks1;
#define TFR(r) { x0 += x1; x1 = rotl32(x1, (r)); x1 ^= x0; }
  TFR(13u) TFR(15u) TFR(26u) TFR(6u)
  x0 += ks1; x1 += ks2 + 1u;
  TFR(17u) TFR(29u) TFR(16u) TFR(24u)
  x0 += ks2; x1 += ks0 + 2u;
  TFR(13u) TFR(15u) TFR(26u) TFR(6u)
  x0 += ks0; x1 += ks1 + 3u;
  TFR(17u) TFR(29u) TFR(16u) TFR(24u)
  x0 += ks1; x1 += ks2 + 4u;
  TFR(13u) TFR(15u) TFR(26u) TFR(6u)
  x0 += ks2; x1 += ks0 + 5u;
#undef TFR
  return x0 ^ x1;
}

// ------------- XLA-CPU (Cephes) float32 log replication ---------------------
__device__ __forceinline__ float xla_logf(float xin) {
  uint32_t bits = __float_as_uint(xin);
  float e = (float)((int)(bits >> 23) - 126);
  float x = __uint_as_float((bits & 0x007fffffu) | 0x3f000000u);
  const float SQRTHF = 0.707106781186547524f;
  bool lt = (x < SQRTHF);
  float tmp = lt ? x : 0.0f;
  e = e - (lt ? 1.0f : 0.0f);
  x = x - 1.0f;
  x = x + tmp;
  float z = x * x;
  float y = 7.0376836292e-2f;
  y = fmaf(y, x, -1.1514610310e-1f);
  y = fmaf(y, x,  1.1676998740e-1f);
  y = fmaf(y, x, -1.2420140846e-1f);
  y = fmaf(y, x,  1.4249322787e-1f);
  y = fmaf(y, x, -1.6668057665e-1f);
  y = fmaf(y, x,  2.0000714765e-1f);
  y = fmaf(y, x, -2.4999993993e-1f);
  y = fmaf(y, x,  3.3333331174e-1f);
  y = y * x;
  y = y * z;
  y = fmaf(e, -2.12194440e-4f, y);
  y = fmaf(-0.5f, z, y);
  x = x + y;
  x = fmaf(e, 0.693359375f, x);
  return x;
}

__device__ __forceinline__ float xla_log1pf(float x) {
  float for_large = xla_logf(x + 1.0f);
  float for_small = fmaf(-0.5f, x, 1.0f) * x;
  return (fabsf(x) < 1e-4f) ? for_small : for_large;
}

// one voxel's decision (exact JAX/XLA bit replication)
__device__ __forceinline__ bool bin_pred(const float* __restrict__ in, uint32_t w,
                                         uint32_t lane) {
  uint32_t row = w / 3u, wx = w - row * 3u;
  uint32_t n  = row / (uint32_t)(PDIM * PDIM);
  uint32_t rr = row - n * (uint32_t)(PDIM * PDIM);
  uint32_t z  = rr / (uint32_t)PDIM;
  uint32_t y  = rr - z * (uint32_t)PDIM;
  uint32_t x  = wx * 64u + lane;
  // pad voxels are provably 0: |0.33*noise| <= 6.08 < 18.42 = |log alpha(0)|
  if ((z - 1u) >= 160u || (y - 1u) >= 160u || (x - 1u) >= 160u) return false;
  float v = in[((n * 160u + (z - 1u)) * 160u + (y - 1u)) * 160u + (x - 1u)];
  uint32_t i = row * 162u + x;            // flat padded index for RNG
  uint32_t b = threefry_bits(i);
  float f  = __uint_as_float((b >> 9) | 0x3f800000u) - 1.0f;
  float uu = fmaxf(1e-8f, f + 1e-8f);
  float la = xla_logf((v + 1e-8f) / ((1.0f - v) + 1e-8f));
  float noise = xla_logf(uu) - xla_log1pf(-uu);
  float zs = la + noise * 0.33f;
  return (zs > 1.1920928955078125e-7f);   // logistic>0.5 iff z>2^-23
}

// ------------- per-word neighborhood from LDS row triples -------------------
#define NB(dz,dy,dx) ((dx)==-1 ? Lb[(dz)+1][(dy)+1] : ((dx)==1 ? Rb[(dz)+1][(dy)+1] : Vv[(dz)+1][(dy)+1]))

// R16 two-phase gather -- ALL 27 row words loaded into explicit locals first
// (wide live range -> batched ds_reads, one lgkmcnt wait), then the per-word
// select/shift compute. Indices compile-time after unroll.
#define GATHER_W(SRC, lz, ly, w) \
  { \
    uint64_t Rr[9][3]; \
    _Pragma("unroll") \
    for (int q = 0; q < 9; ++q) { \
      int rb = LADDR((lz) + (q / 3) - 1, (ly) + (q % 3) - 1); \
      Rr[q][0] = SRC[rb]; Rr[q][1] = SRC[rb + 1]; Rr[q][2] = SRC[rb + 2]; \
    } \
    _Pragma("unroll") \
    for (int q = 0; q < 9; ++q) { \
      uint64_t r0 = Rr[q][0], r1 = Rr[q][1], r2 = Rr[q][2]; \
      uint64_t b = ((w) == 0) ? r0 : (((w) == 1) ? r1 : r2); \
      uint64_t a = ((w) == 0) ? 0ull : (((w) == 1) ? r0 : r1); \
      uint64_t d = ((w) == 0) ? r1 : (((w) == 1) ? r2 : 0ull); \
      Vv[q / 3][q % 3] = b; \
      Lb[q / 3][q % 3] = (b << 1) | (a >> 63); \
      Rb[q / 3][q % 3] = (b >> 1) | (d << 63); \
    } \
  }

// ---- balanced (OR, GE2) reduction: low serial depth for latency hiding ----
struct OG { uint64_t o, g; };
__device__ __forceinline__ OG og_leaf2(uint64_t a, uint64_t b) {
  OG r; r.o = a | b; r.g = a & b; return r;
}
__device__ __forceinline__ OG og_comb(OG a, OG b) {
  OG r; r.g = a.g | b.g | (a.o & b.o); r.o = a.o | b.o; return r;
}

// OG over the 18-neighborhood (faces+edges) and corners; both trees depth ~4.
#define OG_BUILD_18_C(og18, ogc) \
  OG a0 = og_leaf2(NB(-1,0,0), NB(1,0,0)); \
  OG a1 = og_leaf2(NB(0,-1,0), NB(0,1,0)); \
  OG a2 = og_leaf2(NB(0,0,-1), NB(0,0,1)); \
  OG e0 = og_leaf2(NB(-1,-1,0), NB(-1,1,0)); \
  OG e1 = og_leaf2(NB(-1,0,-1), NB(-1,0,1)); \
  OG e2 = og_leaf2(NB(1,-1,0),  NB(1,1,0)); \
  OG e3 = og_leaf2(NB(1,0,-1),  NB(1,0,1)); \
  OG e4 = og_leaf2(NB(0,-1,-1), NB(0,-1,1)); \
  OG e5 = og_leaf2(NB(0,1,-1),  NB(0,1,1)); \
  OG t0 = og_comb(a0, a1); \
  OG t1 = og_comb(a2, e0); \
  OG t2 = og_comb(e1, e2); \
  OG t3 = og_comb(e3, e4); \
  OG og18 = og_comb(og_comb(og_comb(t0, t1), og_comb(t2, t3)), e5); \
  OG c0 = og_leaf2(NB(-1,-1,-1), NB(-1,-1,1)); \
  OG c1 = og_leaf2(NB(-1,1,-1),  NB(-1,1,1)); \
  OG c2 = og_leaf2(NB(1,-1,-1),  NB(1,-1,1)); \
  OG c3 = og_leaf2(NB(1,1,-1),   NB(1,1,1)); \
  OG ogc = og_comb(og_comb(c0, c1), og_comb(c2, c3));

// ge2 (C26>=2) for one word, gathered from the GLOBAL board. z,y in [1,160]
// -> all neighbor rows are in-array; pad rows are stored zeros, so this is
// bit-identical to the per-tile bounds-checked version.
__device__ __forceinline__ uint64_t ge2_word_global(const uint64_t* __restrict__ board,
                                                    int n, int z, int y, int w) {
  uint64_t center = board[((n * 162 + z) * 162 + y) * 3 + w];
  if (center == 0ull) return 0ull;        // ge2 only consumed ANDed with center
  uint64_t Vv[3][3], Lb[3][3], Rb[3][3];
#pragma unroll
  for (int dz = 0; dz < 3; ++dz)
#pragma unroll
    for (int dy = 0; dy < 3; ++dy) {
      const uint64_t* p = board + ((n * 162 + z - 1 + dz) * 162 + (y - 1 + dy)) * 3;
      uint64_t r0 = p[0], r1 = p[1], r2 = p[2];
      uint64_t b = (w == 0) ? r0 : ((w == 1) ? r1 : r2);
      uint64_t a = (w == 0) ? 0ull : ((w == 1) ? r0 : r1);
      uint64_t d = (w == 0) ? r1 : ((w == 1) ? r2 : 0ull);
      Vv[dz][dy] = b;
      Lb[dz][dy] = (b << 1) | (a >> 63);
      Rb[dz][dy] = (b >> 1) | (d << 63);
    }
  OG_BUILD_18_C(og18, ogc)
  return og_comb(og18, ogc).g;
}

// ---------------------------- the whole pipeline ----------------------------
__global__ __launch_bounds__(NTHREADS) void k_all(const float* __restrict__ in,
                                                  float4* __restrict__ outf,
                                                  uint64_t* __restrict__ A,
                                                  uint64_t* __restrict__ B,
                                                  uint64_t* __restrict__ Ge) {
  cg::grid_group gg = cg::this_grid();
  __shared__ uint64_t Bt[TZ * PZ];
  __shared__ uint64_t Gl[TZ * PZ];
  const int tid = threadIdx.x;
  const int bid = blockIdx.x;
  const int gtid = bid * NTHREADS + tid;

  // ---- phase 0a: binarize -> A (wave-ballot, ILP-2, grid-stride) ----
  {
    uint32_t gw = (uint32_t)gtid >> 6, lane = (uint32_t)gtid & 63u;
    const uint32_t nwaves = (GRID * NTHREADS) / 64;
    for (uint32_t w0 = gw; w0 < (uint32_t)NWH; w0 += nwaves) {
      uint32_t w1 = w0 + (uint32_t)NWH;
      bool p0 = bin_pred(in, w0, lane);
      bool p1 = bin_pred(in, w1, lane);
      uint64_t m0 = __ballot(p0);
      uint64_t m1 = __ballot(p1);
      if (lane == 0) { A[w0] = m0; A[w1] = m1; }
    }
  }
  // ---- phase 0b: zero B's pad rows (z or y in {0,161}) once ----
  for (int j = gtid; j < 1288; j += GRID * NTHREADS) {
    int nn, z, y;
    if (j < 648) { nn = j / 324; int r = j - nn * 324;
                   z = (r >= 162) ? 161 : 0; y = (r >= 162) ? r - 162 : r; }
    else { int j2 = j - 648; nn = j2 / 320; int r = j2 - nn * 320;
           y = (r >= 160) ? 161 : 0; z = 1 + ((r >= 160) ? r - 160 : r); }
    uint64_t* p = B + (((nn * 162 + z) * 162) + y) * 3;
    p[0] = 0; p[1] = 0; p[2] = 0;
  }
  __threadfence();
  gg.sync();

  // ---- 5 skeletonization iterations ----
#pragma unroll 1
  for (int it = 0; it < 5; ++it) {
    const uint64_t* __restrict__ src = (it & 1) ? B : A;
    uint64_t* __restrict__ dst = (it & 1) ? A : B;

    // -- phase A: deduplicated ge2 pre-pass (barrier-free streaming) --
    for (int ti = gtid; ti < 2 * 160 * 160 * 3; ti += GRID * NTHREADS) {
      int w = ti % 3;  int r = ti / 3;
      int y = 1 + (r % 160);  int rr = r / 160;
      int z = 1 + (rr % 160); int n = rr / 160;
      Ge[((n * 162 + z) * 162 + y) * 3 + w] = ge2_word_global(src, n, z, y, w);
    }
    __threadfence();
    gg.sync();

    // -- phase B: tile pass (R0 geometry, minus in-block ge2) --
    if (bid < 200) {
      const int n  = bid / 100;
      const int rm = bid - n * 100;
      const int tz = rm / 10, ty = rm - tz * 10;
      const int gz0 = 1 + 16 * tz, gy0 = 1 + 16 * ty;   // both odd

      // load Bt tile + halo 8 (w,ly fastest -> coalesced)
      for (int ti = tid; ti < TZ * TY * 3; ti += NTHREADS) {
        int w = ti % 3, r = ti / 3, ly = r % TY, lz = r / TY;
        int z = gz0 - 8 + lz, y = gy0 - 8 + ly;
        uint64_t v = 0;
        if ((unsigned)z < 162u && (unsigned)y < 162u)
          v = src[((n * 162 + z) * 162 + y) * 3 + w];
        Bt[LADDR(lz, ly) + w] = v;
      }
      // load Ge tile on halo 7 (30x30); Ge valid only at z,y in [1,160]
      for (int ti = tid; ti < 30 * 30 * 3; ti += NTHREADS) {
        int w = ti % 3, r = ti / 3, iy = r % 30, iz = r / 30;
        int z = gz0 - 7 + iz, y = gy0 - 7 + iy;
        uint64_t v = 0;
        if ((unsigned)(z - 1) < 160u && (unsigned)(y - 1) < 160u)
          v = Ge[((n * 162 + z) * 162 + y) * 3 + w];
        Gl[LADDR(1 + iz, 1 + iy) + w] = v;
      }
      __syncthreads();

      // 8 subfield passes, halo 7-k, parity per reference offsets order
      const int PLZ[8] = {1,0,1,0,1,0,1,0};  // lz parity (xo=0 -> z even -> lz odd)
      const int PLY[8] = {1,1,0,0,1,1,0,0};  // ly parity
#pragma unroll
      for (int k = 0; k < 8; ++k) {
        const int h = 7 - k, cnt1 = 8 + h;
        const uint64_t xmask = (k < 4) ? 0x5555555555555555ull : 0xAAAAAAAAAAAAAAAAull;
        const int s0 = 8 - h;
        const int slz = s0 + ((s0 ^ PLZ[k]) & 1);
        const int sly = s0 + ((s0 ^ PLY[k]) & 1);
        for (int ti = tid; ti < cnt1 * cnt1 * 3; ti += NTHREADS) {
          int w = ti % 3, r = ti / 3, iy = r % cnt1, iz = r / cnt1;
          int lz = slz + 2 * iz, ly = sly + 2 * iy;
          int base = LADDR(lz, ly) + w;
          uint64_t center = Bt[base];
          uint64_t act = center & xmask & Gl[base];
          if (act == 0ull) continue;
          uint64_t Vv[3][3], Lb[3][3], Rb[3][3];
          GATHER_W(Bt, lz, ly, w)

          // tree (OR,GE2) over 18-set and corners
          OG_BUILD_18_C(og18, ogc)
          OG og26 = og_comb(og18, ogc);
          uint64_t e18 = og18.o & ~og18.g;  // C18 == 1
          uint64_t e26 = og26.o & ~og26.g;  // C26 == 1

          // C6 via complemented faces: eq5 = exactly-1 missing, le4 = >=2 missing
          uint64_t m0f = ~NB(-1,0,0), m1f = ~NB(1,0,0), m2f = ~NB(0,-1,0);
          uint64_t m3f = ~NB(0,1,0),  m4f = ~NB(0,0,-1), m5f = ~NB(0,0,1);
          OG p0 = og_leaf2(m0f, m1f);
          OG p1 = og_leaf2(m2f, m3f);
          OG p2 = og_leaf2(m4f, m5f);
          OG pm = og_comb(og_comb(p0, p1), p2);
          uint64_t c6eq5 = pm.o & ~pm.g;
          uint64_t c6le4 = pm.g;

          uint64_t del = (c6eq5 | e26) & act;
          // B/A patterns only where a candidate isn't already decided
          uint64_t need = act & ~del & (e18 | c6le4);
          if (need != 0ull) {
            // B: corner set with its 6 octant face/edge cells all clear
            uint64_t badB = 0;
#pragma unroll
            for (int sz = -1; sz <= 1; sz += 2)
#pragma unroll
              for (int sy = -1; sy <= 1; sy += 2)
#pragma unroll
                for (int sx = -1; sx <= 1; sx += 2) {
                  uint64_t oct = NB(sz,0,0) | NB(0,sy,0) | NB(0,0,sx)
                               | NB(sz,sy,0) | NB(sz,0,sx) | NB(0,sy,sx);
                  badB |= NB(sz,sy,sx) & ~oct;
                }
            uint64_t b0ok = ~badB;

            // A: face clear with its full 4-cell in-plane ring set
            uint64_t badA = 0;
            badA |= ~NB(-1,0,0) & NB(-1,-1,0) & NB(-1,1,0) & NB(-1,0,-1) & NB(-1,0,1);
            badA |= ~NB( 1,0,0) & NB( 1,-1,0) & NB( 1,1,0) & NB( 1,0,-1) & NB( 1,0,1);
            badA |= ~NB(0,-1,0) & NB(-1,-1,0) & NB(1,-1,0) & NB(0,-1,-1) & NB(0,-1,1);
            badA |= ~NB(0, 1,0) & NB(-1, 1,0) & NB(1, 1,0) & NB(0, 1,-1) & NB(0, 1,1);
            badA |= ~NB(0,0,-1) & NB(-1,0,-1) & NB(1,0,-1) & NB(0,-1,-1) & NB(0,1,-1);
            badA |= ~NB(0,0, 1) & NB(-1,0, 1) & NB(1,0, 1) & NB(0,-1, 1) & NB(0,1, 1);
            uint64_t a0ok = ~badA;

            del |= ((e18 & b0ok) | (c6le4 & a0ok & b0ok)) & act;
          }
          if (del) Bt[base] = center & ~del;
          // readers only consume non-updated-parity bits; tearing-safe (R5 arg)
        }
        __syncthreads();
      }

      // epilogue
      if (it == 4) {
        // final iteration: write float output for core directly from LDS
        for (int ti = tid; ti < CZ * CY * 40; ti += NTHREADS) {
          int g = ti % 40, r = ti / 40, iy = r % CY, iz = r / CY;
          int base = LADDR(8 + iz, 8 + iy);
          int bi = 1 + 4 * g;               // padded x of first of 4 floats
          int wx = bi >> 6, sft = bi & 63;
          uint64_t v = Bt[base + wx] >> sft;
          if (sft > 60) v |= Bt[base + wx + 1] << (64 - sft);
          outf[((n * 160 + (gz0 + iz - 1)) * 160 + (gy0 + iy - 1)) * 40 + g] =
              make_float4((float)(v & 1u), (float)((v >> 1) & 1u),
                          (float)((v >> 2) & 1u), (float)((v >> 3) & 1u));
        }
      } else {
        // write core words back (disjoint across blocks)
        for (int ti = tid; ti < CZ * CY * 3; ti += NTHREADS) {
          int w = ti % 3, r = ti / 3, iy = r % CY, iz = r / CY;
          dst[((n * 162 + gz0 + iz) * 162 + (gy0 + iy)) * 3 + w] =
              Bt[LADDR(8 + iz, 8 + iy) + w];
        }
      }
    }
    __threadfence();
    if (it < 4) gg.sync();
  }
}

// ---------------------------- launcher --------------------------------------
extern "C" void kernel_launch(void* const* d_in, const int* in_sizes, int n_in,
                              void* d_out, int out_size, void* d_ws, size_t ws_size,
                              hipStream_t stream) {
  const float* in = (const float*)d_in[0];
  float4* out = (float4*)d_out;
  uint64_t* A = (uint64_t*)d_ws;          // bitboard A
  uint64_t* B = A + NW;                   // bitboard B
  uint64_t* Ge = B + NW;                  // ge2 (not-endpoint) board

  void* args[] = { (void*)&in, (void*)&out, (void*)&A, (void*)&B, (void*)&Ge };
  hipLaunchCooperativeKernel((const void*)k_all, dim3(GRID), dim3(NTHREADS),
                             args, 0, stream);
}

// Round 7
// 213.218 us; speedup vs baseline: 6.5079x; 6.5079x over previous
//
#include <hip/hip_runtime.h>
#include <stdint.h>

// No implicit FMA contraction: the JAX eager reference has none across ops;
// where XLA fuses we write fmaf() explicitly.
#pragma clang fp contract(off)

#define PDIM 162
#define NW   (2*PDIM*PDIM*3)   // 157464 words, 1.26 MB per bitboard
#define NWH  (NW/2)            // 78732
#define OD   160

// R18 = R0 champion kernel (220.8us) untouched, EXCEPT bin_pred: fast-path
// decision via hardware v_log_f32 (log2, ~1ulp) with exact-Cephes fallback
// when |zs_fast - T| <= 3e-4 (error bound ~6e-6 -> 50x margin; ~1% of waves
// take the fallback). Output remains bit-identical (guard: absmax == 0).
// R1-R6 lesson: k_iter restructures (tile shape, ge2 fusion/dedup, wide
// gather, cooperative grid) are all neutral-to-catastrophic; binarize is the
// one remaining well-understood VALU-bound consumer (~42us, VALUBusy 107%).
#define PZ 97
#define LADDR(lz,ly) ((lz)*PZ + (ly)*3)

// ---------------- threefry2x32, JAX partitionable scheme --------------------
__device__ __forceinline__ uint32_t rotl32(uint32_t x, uint32_t r) {
  return (x << r) | (x >> (32u - r));
}

__device__ __forceinline__ uint32_t threefry_bits(uint32_t idx) {
  const uint32_t ks0 = 0u, ks1 = 42u, ks2 = 0x1BD11BDAu ^ 0u ^ 42u;
  uint32_t x0 = 0u + ks0;
  uint32_t x1 = idx + ks1;
#define TFR(r) { x0 += x1; x1 = rotl32(x1, (r)); x1 ^= x0; }
  TFR(13u) TFR(15u) TFR(26u) TFR(6u)
  x0 += ks1; x1 += ks2 + 1u;
  TFR(17u) TFR(29u) TFR(16u) TFR(24u)
  x0 += ks2; x1 += ks0 + 2u;
  TFR(13u) TFR(15u) TFR(26u) TFR(6u)
  x0 += ks0; x1 += ks1 + 3u;
  TFR(17u) TFR(29u) TFR(16u) TFR(24u)
  x0 += ks1; x1 += ks2 + 4u;
  TFR(13u) TFR(15u) TFR(26u) TFR(6u)
  x0 += ks2; x1 += ks0 + 5u;
#undef TFR
  return x0 ^ x1;
}

// ------------- XLA-CPU (Cephes) float32 log replication ---------------------
__device__ __forceinline__ float xla_logf(float xin) {
  uint32_t bits = __float_as_uint(xin);
  float e = (float)((int)(bits >> 23) - 126);
  float x = __uint_as_float((bits & 0x007fffffu) | 0x3f000000u);
  const float SQRTHF = 0.707106781186547524f;
  bool lt = (x < SQRTHF);
  float tmp = lt ? x : 0.0f;
  e = e - (lt ? 1.0f : 0.0f);
  x = x - 1.0f;
  x = x + tmp;
  float z = x * x;
  float y = 7.0376836292e-2f;
  y = fmaf(y, x, -1.1514610310e-1f);
  y = fmaf(y, x,  1.1676998740e-1f);
  y = fmaf(y, x, -1.2420140846e-1f);
  y = fmaf(y, x,  1.4249322787e-1f);
  y = fmaf(y, x, -1.6668057665e-1f);
  y = fmaf(y, x,  2.0000714765e-1f);
  y = fmaf(y, x, -2.4999993993e-1f);
  y = fmaf(y, x,  3.3333331174e-1f);
  y = y * x;
  y = y * z;
  y = fmaf(e, -2.12194440e-4f, y);
  y = fmaf(-0.5f, z, y);
  x = x + y;
  x = fmaf(e, 0.693359375f, x);
  return x;
}

__device__ __forceinline__ float xla_log1pf(float x) {
  float for_large = xla_logf(x + 1.0f);
  float for_small = fmaf(-0.5f, x, 1.0f) * x;
  return (fabsf(x) < 1e-4f) ? for_small : for_large;
}

// one voxel's decision (bit-exact JAX/XLA replication; fast-path + fallback)
__device__ __forceinline__ bool bin_pred(const float* __restrict__ in, uint32_t w,
                                         uint32_t lane) {
  uint32_t row = w / 3u, wx = w - row * 3u;
  uint32_t n  = row / (uint32_t)(PDIM * PDIM);
  uint32_t rr = row - n * (uint32_t)(PDIM * PDIM);
  uint32_t z  = rr / (uint32_t)PDIM;
  uint32_t y  = rr - z * (uint32_t)PDIM;
  uint32_t x  = wx * 64u + lane;
  // pad voxels are provably 0: |0.33*noise| <= 6.08 < 18.42 = |log alpha(0)|
  if ((z - 1u) >= 160u || (y - 1u) >= 160u || (x - 1u) >= 160u) return false;
  float v = in[((n * 160u + (z - 1u)) * 160u + (y - 1u)) * 160u + (x - 1u)];
  uint32_t i = row * 162u + x;            // flat padded index for RNG
  uint32_t b = threefry_bits(i);
  float f  = __uint_as_float((b >> 9) | 0x3f800000u) - 1.0f;
  float uu = fmaxf(1e-8f, f + 1e-8f);
  float h  = (v + 1e-8f) / ((1.0f - v) + 1e-8f);   // shared with exact path
  const float T = 1.1920928955078125e-7f;          // logistic>0.5 iff z>2^-23

  // ---- fast path: v_log_f32 (log2) x3. |zs_f - zs_cephes| <= ~6e-6:
  // each log ~1-2 ulp of a |log2|<=27 result (~4e-6 in ln units after *ln2),
  // div/round-off ~1e-7. Decide when outside 3e-4 of the threshold (50x
  // margin); ~7e-5 of samples fall inside -> exact Cephes fallback.
  const float LN2 = 0.6931471805599453f;
  float la_f = __builtin_amdgcn_logf(h) * LN2;
  float nz_f = (__builtin_amdgcn_logf(uu) - __builtin_amdgcn_logf(1.0f - uu)) * LN2;
  float zs_f = fmaf(nz_f, 0.33f, la_f);
  if (fabsf(zs_f - T) > 3.0e-4f) return zs_f > T;

  // ---- exact Cephes fallback (bit-identical to XLA) ----
  float la = xla_logf(h);
  float noise = xla_logf(uu) - xla_log1pf(-uu);
  float zs = la + noise * 0.33f;
  return zs > T;
}

// ---------------------------- binarize --------------------------------------
// ILP-2: each wave produces TWO words (w and w+NW/2).
__global__ __launch_bounds__(256) void k_binarize(const float* __restrict__ in,
                                                  uint64_t* __restrict__ bits) {
  uint32_t t = blockIdx.x * 256u + threadIdx.x;
  uint32_t w0 = t >> 6, lane = t & 63u;
  if (w0 >= (uint32_t)NWH) return;        // wave-uniform
  uint32_t w1 = w0 + (uint32_t)NWH;
  bool p0 = bin_pred(in, w0, lane);
  bool p1 = bin_pred(in, w1, lane);
  uint64_t m0 = __ballot(p0);
  uint64_t m1 = __ballot(p1);
  if (lane == 0) { bits[w0] = m0; bits[w1] = m1; }
}

// ------------- per-word neighborhood from LDS row triples -------------------
#define NB(dz,dy,dx) ((dx)==-1 ? Lb[(dz)+1][(dy)+1] : ((dx)==1 ? Rb[(dz)+1][(dy)+1] : Vv[(dz)+1][(dy)+1]))

#define GATHER_W(SRC, lz, ly, w) \
  _Pragma("unroll") \
  for (int dz = 0; dz < 3; ++dz) \
    _Pragma("unroll") \
    for (int dy = 0; dy < 3; ++dy) { \
      int rb = LADDR((lz) + dz - 1, (ly) + dy - 1); \
      uint64_t r0 = SRC[rb], r1 = SRC[rb + 1], r2 = SRC[rb + 2]; \
      uint64_t b = ((w) == 0) ? r0 : (((w) == 1) ? r1 : r2); \
      uint64_t a = ((w) == 0) ? 0ull : (((w) == 1) ? r0 : r1); \
      uint64_t d = ((w) == 0) ? r1 : (((w) == 1) ? r2 : 0ull); \
      Vv[dz][dy] = b; \
      Lb[dz][dy] = (b << 1) | (a >> 63); \
      Rb[dz][dy] = (b >> 1) | (d << 63); \
    }

// ---- balanced (OR, GE2) reduction: low serial depth for latency hiding ----
struct OG { uint64_t o, g; };
__device__ __forceinline__ OG og_leaf2(uint64_t a, uint64_t b) {
  OG r; r.o = a | b; r.g = a & b; return r;
}
__device__ __forceinline__ OG og_comb(OG a, OG b) {
  OG r; r.g = a.g | b.g | (a.o & b.o); r.o = a.o | b.o; return r;
}

// OG over the 18-neighborhood (faces+edges) and corners; both trees depth ~4.
#define OG_BUILD_18_C(og18, ogc) \
  OG a0 = og_leaf2(NB(-1,0,0), NB(1,0,0)); \
  OG a1 = og_leaf2(NB(0,-1,0), NB(0,1,0)); \
  OG a2 = og_leaf2(NB(0,0,-1), NB(0,0,1)); \
  OG e0 = og_leaf2(NB(-1,-1,0), NB(-1,1,0)); \
  OG e1 = og_leaf2(NB(-1,0,-1), NB(-1,0,1)); \
  OG e2 = og_leaf2(NB(1,-1,0),  NB(1,1,0)); \
  OG e3 = og_leaf2(NB(1,0,-1),  NB(1,0,1)); \
  OG e4 = og_leaf2(NB(0,-1,-1), NB(0,-1,1)); \
  OG e5 = og_leaf2(NB(0,1,-1),  NB(0,1,1)); \
  OG t0 = og_comb(a0, a1); \
  OG t1 = og_comb(a2, e0); \
  OG t2 = og_comb(e1, e2); \
  OG t3 = og_comb(e3, e4); \
  OG og18 = og_comb(og_comb(og_comb(t0, t1), og_comb(t2, t3)), e5); \
  OG c0 = og_leaf2(NB(-1,-1,-1), NB(-1,-1,1)); \
  OG c1 = og_leaf2(NB(-1,1,-1),  NB(-1,1,1)); \
  OG c2 = og_leaf2(NB(1,-1,-1),  NB(1,-1,1)); \
  OG c3 = og_leaf2(NB(1,1,-1),   NB(1,1,1)); \
  OG ogc = og_comb(og_comb(c0, c1), og_comb(c2, c3));

// ---------------------------- iteration kernel ------------------------------
// One block: 16x16 (z,y) core x full 192-bit x, halo 8 -> 32x32 LDS tile.
// ge2 on halo 7, then 8 subfield passes with shrinking halo; writes core only
// (or, final iteration, the float output directly from LDS).
__global__ __launch_bounds__(1024) void k_iter(const uint64_t* __restrict__ bin,
                                               uint64_t* __restrict__ bout,
                                               float4* __restrict__ outf,
                                               int zero_pads) {
  __shared__ uint64_t Bt[32 * PZ];
  __shared__ uint64_t Ge[32 * PZ];
  const int tid = threadIdx.x;
  const int bid = blockIdx.x;
  const int n  = bid / 100;
  const int rm = bid - n * 100;
  const int tz = rm / 10, ty = rm - tz * 10;
  const int gz0 = 1 + 16 * tz, gy0 = 1 + 16 * ty;   // both odd

  // Zero bout's pad rows (z or y in {0,161}) once per replay (block 0, iter 1).
  if (zero_pads && bid == 0) {
    for (int j = tid; j < 1288; j += 1024) {
      int nn, z, y;
      if (j < 648) { nn = j / 324; int r = j - nn * 324;
                     z = (r >= 162) ? 161 : 0; y = (r >= 162) ? r - 162 : r; }
      else { int j2 = j - 648; nn = j2 / 320; int r = j2 - nn * 320;
             y = (r >= 160) ? 161 : 0; z = 1 + ((r >= 160) ? r - 160 : r); }
      uint64_t* p = bout + (((nn * 162 + z) * 162) + y) * 3;
      p[0] = 0; p[1] = 0; p[2] = 0;
    }
  }

  // ---- load tile + halo 8 (w,ly fastest -> coalesced global reads) ----
  for (int ti = tid; ti < 32 * 32 * 3; ti += 1024) {
    int w = ti % 3, r = ti / 3, ly = r % 32, lz = r / 32;
    int z = gz0 - 8 + lz, y = gy0 - 8 + ly;
    uint64_t v = 0;
    if ((unsigned)z < 162u && (unsigned)y < 162u)
      v = bin[((n * 162 + z) * 162 + y) * 3 + w];
    Bt[LADDR(lz, ly) + w] = v;
  }
  __syncthreads();

  // ---- ge2 (C26>=2, not-endpoint) on halo 7 (30x30), tree reduction ----
  for (int ti = tid; ti < 30 * 30 * 3; ti += 1024) {
    int w = ti % 3, r = ti / 3, iy = r % 30, iz = r / 30;
    int lz = 1 + iz, ly = 1 + iy;
    int base = LADDR(lz, ly) + w;
    uint64_t res = 0;
    if (Bt[base] != 0ull) {               // ge2 only consumed ANDed with center
      uint64_t Vv[3][3], Lb[3][3], Rb[3][3];
      GATHER_W(Bt, lz, ly, w)
      OG_BUILD_18_C(og18, ogc)
      res = og_comb(og18, ogc).g;         // GE2 over all 26
    }
    Ge[base] = res;
  }
  __syncthreads();

  // ---- 8 subfield passes, halo 7-k, parity per reference offsets order ----
  const int PLZ[8] = {1,0,1,0,1,0,1,0};   // lz parity (xo=0 -> z even -> lz odd)
  const int PLY[8] = {1,1,0,0,1,1,0,0};   // ly parity
#pragma unroll
  for (int k = 0; k < 8; ++k) {
    const int h = 7 - k, cnt1 = 8 + h;
    const uint64_t xmask = (k < 4) ? 0x5555555555555555ull : 0xAAAAAAAAAAAAAAAAull;
    const int s0 = 8 - h;
    const int slz = s0 + ((s0 ^ PLZ[k]) & 1);
    const int sly = s0 + ((s0 ^ PLY[k]) & 1);
    for (int ti = tid; ti < cnt1 * cnt1 * 3; ti += 1024) {
      int w = ti % 3, r = ti / 3, iy = r % cnt1, iz = r / cnt1;
      int lz = slz + 2 * iz, ly = sly + 2 * iy;
      int base = LADDR(lz, ly) + w;
      uint64_t center = Bt[base];
      uint64_t act = center & xmask & Ge[base];
      if (act == 0ull) continue;
      uint64_t Vv[3][3], Lb[3][3], Rb[3][3];
      GATHER_W(Bt, lz, ly, w)

      // tree (OR,GE2) over 18-set and corners
      OG_BUILD_18_C(og18, ogc)
      OG og26 = og_comb(og18, ogc);
      uint64_t e18 = og18.o & ~og18.g;    // C18 == 1
      uint64_t e26 = og26.o & ~og26.g;    // C26 == 1

      // C6 via complemented faces: eq5 = exactly-1 missing, le4 = >=2 missing
      uint64_t m0f = ~NB(-1,0,0), m1f = ~NB(1,0,0), m2f = ~NB(0,-1,0);
      uint64_t m3f = ~NB(0,1,0),  m4f = ~NB(0,0,-1), m5f = ~NB(0,0,1);
      OG p0 = og_leaf2(m0f, m1f);
      OG p1 = og_leaf2(m2f, m3f);
      OG p2 = og_leaf2(m4f, m5f);
      OG pm = og_comb(og_comb(p0, p1), p2);
      uint64_t c6eq5 = pm.o & ~pm.g;
      uint64_t c6le4 = pm.g;

      uint64_t del = (c6eq5 | e26) & act;
      // B/A patterns only where a candidate isn't already decided
      uint64_t need = act & ~del & (e18 | c6le4);
      if (need != 0ull) {
        // B: corner set with its 6 octant face/edge cells all clear
        uint64_t badB = 0;
#pragma unroll
        for (int sz = -1; sz <= 1; sz += 2)
#pragma unroll
          for (int sy = -1; sy <= 1; sy += 2)
#pragma unroll
            for (int sx = -1; sx <= 1; sx += 2) {
              uint64_t oct = NB(sz,0,0) | NB(0,sy,0) | NB(0,0,sx)
                           | NB(sz,sy,0) | NB(sz,0,sx) | NB(0,sy,sx);
              badB |= NB(sz,sy,sx) & ~oct;
            }
        uint64_t b0ok = ~badB;

        // A: face clear with its full 4-cell in-plane ring set
        uint64_t badA = 0;
        badA |= ~NB(-1,0,0) & NB(-1,-1,0) & NB(-1,1,0) & NB(-1,0,-1) & NB(-1,0,1);
        badA |= ~NB( 1,0,0) & NB( 1,-1,0) & NB( 1,1,0) & NB( 1,0,-1) & NB( 1,0,1);
        badA |= ~NB(0,-1,0) & NB(-1,-1,0) & NB(1,-1,0) & NB(0,-1,-1) & NB(0,-1,1);
        badA |= ~NB(0, 1,0) & NB(-1, 1,0) & NB(1, 1,0) & NB(0, 1,-1) & NB(0, 1,1);
        badA |= ~NB(0,0,-1) & NB(-1,0,-1) & NB(1,0,-1) & NB(0,-1,-1) & NB(0,1,-1);
        badA |= ~NB(0,0, 1) & NB(-1,0, 1) & NB(1,0, 1) & NB(0,-1, 1) & NB(0,1, 1);
        uint64_t a0ok = ~badA;

        del |= ((e18 & b0ok) | (c6le4 & a0ok & b0ok)) & act;
      }
      if (del) Bt[base] = center & ~del;
      // readers only consume non-updated-parity bits; tearing-safe (R5 arg)
    }
    __syncthreads();
  }

  // ---- epilogue ----
  if (outf) {
    // final iteration: write float output for core directly from LDS
    for (int ti = tid; ti < 16 * 16 * 40; ti += 1024) {
      int g = ti % 40, r = ti / 40, iy = r % 16, iz = r / 16;
      int base = LADDR(8 + iz, 8 + iy);
      int bi = 1 + 4 * g;                 // padded x of first of 4 floats
      int wx = bi >> 6, sft = bi & 63;
      uint64_t v = Bt[base + wx] >> sft;
      if (sft > 60) v |= Bt[base + wx + 1] << (64 - sft);
      outf[((n * 160 + (gz0 + iz - 1)) * 160 + (gy0 + iy - 1)) * 40 + g] =
          make_float4((float)(v & 1u), (float)((v >> 1) & 1u),
                      (float)((v >> 2) & 1u), (float)((v >> 3) & 1u));
    }
  } else {
    // write core words back (disjoint across blocks)
    for (int ti = tid; ti < 16 * 16 * 3; ti += 1024) {
      int w = ti % 3, r = ti / 3, iy = r % 16, iz = r / 16;
      bout[((n * 162 + gz0 + iz) * 162 + (gy0 + iy)) * 3 + w] =
          Bt[LADDR(8 + iz, 8 + iy) + w];
    }
  }
}

// ---------------------------- launcher --------------------------------------
extern "C" void kernel_launch(void* const* d_in, const int* in_sizes, int n_in,
                              void* d_out, int out_size, void* d_ws, size_t ws_size,
                              hipStream_t stream) {
  const float* in = (const float*)d_in[0];
  float4* out = (float4*)d_out;
  uint64_t* A = (uint64_t*)d_ws;          // bitboard A
  uint64_t* B = A + NW;                   // bitboard B

  k_binarize<<<dim3((NWH * 64 + 255) / 256), dim3(256), 0, stream>>>(in, A);
  k_iter<<<dim3(200), dim3(1024), 0, stream>>>(A, B, nullptr, 1); // iter 1
  k_iter<<<dim3(200), dim3(1024), 0, stream>>>(B, A, nullptr, 0); // iter 2
  k_iter<<<dim3(200), dim3(1024), 0, stream>>>(A, B, nullptr, 0); // iter 3
  k_iter<<<dim3(200), dim3(1024), 0, stream>>>(B, A, nullptr, 0); // iter 4
  k_iter<<<dim3(200), dim3(1024), 0, stream>>>(A, nullptr, out, 0); // iter 5 -> out
}